// Round 2
// 170.870 us; speedup vs baseline: 1.0148x; 1.0148x over previous
//
#include <hip/hip_runtime.h>
#include <math.h>

#define NN   1024
#define FF   32
#define HID  64
#define OUTF 32
#define ITER 8

typedef unsigned int  uint;
typedef unsigned short ushort;
typedef _Float16 halfx8  __attribute__((ext_vector_type(8)));
typedef __fp16   fp16x2  __attribute__((ext_vector_type(2)));
typedef float    floatx16 __attribute__((ext_vector_type(16)));

// ws layout (float offsets)
#define WS_A    0                      // N*HID
#define WS_B    (WS_A + NN*HID)        // 65536
#define WS_C4   (WS_B + NN*HID)        // 131072  (N x 4: x,y,z,0)
#define WS_B1   (WS_C4 + NN*4)         // 135168
#define WS_B2   (WS_B1 + HID)          // 135232 (pad to 64)
#define WS_W2H  (WS_B2 + 64)           // 135296  ushort[4*64*8] = 1024 floats

__device__ __forceinline__ float swish(float x) {
    // x * sigmoid(x); v_exp_f32 / v_rcp_f32, abs err ~1e-5 max — far under budget
    float e = __builtin_amdgcn_exp2f(x * -1.442695040888963f);
    return x * __builtin_amdgcn_rcpf(1.0f + e);
}

__global__ void prep_kernel(
    const float* __restrict__ Coords,
    const float* __restrict__ Emb,
    const float* __restrict__ W1,
    const float* __restrict__ b1,
    const float* __restrict__ W2,
    const float* __restrict__ b2,
    float* __restrict__ ws)
{
    const int b = blockIdx.x;
    const int t = threadIdx.x;
    if (b < NN) {
        // A[b][t] = sum_f Emb[b,f]*W1[t,f];  B[b][t] = sum_f Emb[b,f]*W1[t,F+f]
        float accA = 0.f, accB = 0.f;
        const float* w1row = W1 + t * (2 * FF);
        const float* erow  = Emb + b * FF;
        #pragma unroll
        for (int f = 0; f < FF; ++f) {
            float e = erow[f];
            accA = fmaf(e, w1row[f],      accA);
            accB = fmaf(e, w1row[FF + f], accB);
        }
        ws[WS_A + b * HID + t] = accA;
        ws[WS_B + b * HID + t] = accB;
    } else {
        if (t < HID)  ws[WS_B1 + t] = b1[t];
        if (t < OUTF) ws[WS_B2 + t] = b2[t];
        #pragma unroll 1
        for (int n = t; n < NN; n += 64) {
            ws[WS_C4 + n * 4 + 0] = Coords[n * 3 + 0];
            ws[WS_C4 + n * 4 + 1] = Coords[n * 3 + 1];
            ws[WS_C4 + n * 4 + 2] = Coords[n * 3 + 2];
            ws[WS_C4 + n * 4 + 3] = 0.f;
        }
        // W2^T fragments in MFMA B-layout (32x32x16): n = t&31, k = (t>>5)*8 + j
        // f16 RNE (2^-11 rel err) — 4x finer than the previous bf16 path
        ushort* w2h = (ushort*)(ws + WS_W2H);
        const int n  = t & 31;
        const int kh = (t >> 5) * 8;
        #pragma unroll
        for (int c = 0; c < 4; ++c) {
            #pragma unroll
            for (int j = 0; j < 8; ++j) {
                const int k = c * 16 + kh + j;
                union { _Float16 h; ushort u; } cv;
                cv.h = (_Float16)W2[n * HID + k];
                w2h[(c * 64 + t) * 8 + j] = cv.u;
            }
        }
    }
}

// Block = 256 thr = 4 waves. Wave owns a fixed 32-j tile, loops over ITER i's.
// 32x32x16 f16 MFMA: M = 32 pairs (j), N = 32 outs, K = 64 hid (4 chunks of 16).
// Lane L: pair p = L&31, hid-slice k = c*16 + (L>>5)*8 + jj  (A-fragment layout).
// h1 -> f16 via v_cvt_pkrtz (1 instr / 2 elements) — replaces the old bf16
// hi+lo split (and+sub+shift+pack, 2x MFMA). f16 RTZ h1 (2^-10) + f16 RNE W2
// (2^-11) bounds the output error below the old bf16-RNE-W2 (2^-9) term.
__global__ __launch_bounds__(256, 4) void main_kernel(
    const float* __restrict__ Edges,
    const float* __restrict__ ws,
    float* __restrict__ out)
{
    __shared__ float lds[ITER * HID + HID + ITER * 4]; // A rows | b1 | ci rows

    const int t    = threadIdx.x;
    const int lane = t & 63;
    const int wave = t >> 6;
    const int j0   = blockIdx.x * 128 + wave * 32;
    const int i0   = blockIdx.y * ITER;
    const int p    = lane & 31;
    const int half = lane >> 5;
    const int jp   = j0 + p;

    // ---- stage LDS: A[i0..i0+7][64], b1[64], C4[i0..i0+7] ----
    {
        const float* srcA = ws + WS_A + (size_t)i0 * HID;   // 512 contiguous floats
        if (t < 128) {
            *(float4*)&lds[t * 4] = *(const float4*)(srcA + t * 4);
        } else if (t < 144) {
            *(float4*)&lds[ITER * HID + (t - 128) * 4] =
                *(const float4*)(ws + WS_B1 + (t - 128) * 4);
        } else if (t < 152) {
            *(float4*)&lds[ITER * HID + HID + (t - 144) * 4] =
                *(const float4*)(ws + WS_C4 + (size_t)(i0 + (t - 144)) * 4);
        }
    }

    // ---- loop-invariant state (VGPRs) ----
    const ushort* w2hp = (const ushort*)(ws + WS_W2H);
    halfx8 bh[4];
    #pragma unroll
    for (int c = 0; c < 4; ++c)
        bh[c] = *(const halfx8*)(w2hp + (c * 64 + lane) * 8);

    const float* __restrict__ Bj = ws + WS_B + (size_t)jp * HID;
    float bv[4][8];
    #pragma unroll
    for (int c = 0; c < 4; ++c) {
        const int h0 = c * 16 + half * 8;
        *(float4*)(&bv[c][0]) = *(const float4*)(Bj + h0);
        *(float4*)(&bv[c][4]) = *(const float4*)(Bj + h0 + 4);
    }
    const float4 cj  = *(const float4*)(ws + WS_C4 + (size_t)jp * 4);
    const float  b2n = ws[WS_B2 + p];

    __syncthreads();

    // Edges software pipeline
    const float* egp = Edges + (size_t)i0 * NN + jp;
    float eg = *egp;

    #pragma unroll 1
    for (int it = 0; it < ITER; ++it) {
        const int i = i0 + it;
        const float eg_cur = eg;
        if (it + 1 < ITER) eg = egp[(size_t)(it + 1) * NN];  // prefetch next row

        // ci via LDS broadcast (all lanes same addr = free)
        const float4 civ = *(const float4*)&lds[ITER * HID + HID + it * 4];
        const float dx = civ.x - cj.x, dy = civ.y - cj.y, dz = civ.z - cj.z;
        const float dist = sqrtf(dx * dx + dy * dy + dz * dz);
        const float w = eg_cur * dist;

        // layer-1 + swish; pack straight to f16 (RTZ) — no residual pass
        union FragH { fp16x2 h2[4]; halfx8 v; } ah[4];
        #pragma unroll
        for (int c = 0; c < 4; ++c) {
            const int ho = c * 16 + half * 8;
            float av[8], b1c[8];
            *(float4*)(av + 0)  = *(const float4*)&lds[it * HID + ho];
            *(float4*)(av + 4)  = *(const float4*)&lds[it * HID + ho + 4];
            *(float4*)(b1c + 0) = *(const float4*)&lds[ITER * HID + ho];
            *(float4*)(b1c + 4) = *(const float4*)&lds[ITER * HID + ho + 4];
            #pragma unroll
            for (int jj = 0; jj < 8; jj += 2) {
                const float p0 = fmaf(w, av[jj]     + bv[c][jj],     b1c[jj]);
                const float p1 = fmaf(w, av[jj + 1] + bv[c][jj + 1], b1c[jj + 1]);
                ah[c].h2[jj >> 1] = __builtin_amdgcn_cvt_pkrtz(swish(p0), swish(p1));
            }
        }

        // layer-2 GEMM: pre2 = h1 @ W2^T   (4 f16 MFMAs, single pass)
        floatx16 acc = {0.f,0.f,0.f,0.f,0.f,0.f,0.f,0.f,
                        0.f,0.f,0.f,0.f,0.f,0.f,0.f,0.f};
        #pragma unroll
        for (int c = 0; c < 4; ++c)
            acc = __builtin_amdgcn_mfma_f32_32x32x16_f16(ah[c].v, bh[c], acc, 0, 0, 0);

        // epilogue: C/D layout n = lane&31, m = (r&3) + 8*(r>>2) + 4*half
        // nontemporal: streaming writes must not evict the L2 working set
        float* __restrict__ ob = out + ((size_t)i * NN + j0) * OUTF + p;
        #pragma unroll
        for (int r = 0; r < 16; ++r) {
            const int m = (r & 3) + 8 * (r >> 2) + 4 * half;
            __builtin_nontemporal_store(swish(acc[r] + b2n), ob + m * OUTF);
        }
    }
}

extern "C" void kernel_launch(void* const* d_in, const int* in_sizes, int n_in,
                              void* d_out, int out_size, void* d_ws, size_t ws_size,
                              hipStream_t stream)
{
    const float* Edges  = (const float*)d_in[0];
    const float* Coords = (const float*)d_in[1];
    const float* Emb    = (const float*)d_in[2];
    const float* W1     = (const float*)d_in[3];
    const float* b1     = (const float*)d_in[4];
    const float* W2     = (const float*)d_in[5];
    const float* b2     = (const float*)d_in[6];
    float* ws  = (float*)d_ws;
    float* out = (float*)d_out;

    hipLaunchKernelGGL(prep_kernel, dim3(NN + 1), dim3(64), 0, stream,
                       Coords, Emb, W1, b1, W2, b2, ws);
    hipLaunchKernelGGL(main_kernel, dim3(NN / 128, NN / ITER), dim3(256), 0, stream,
                       Edges, ws, out);
}